// Round 6
// baseline (1021.283 us; speedup 1.0000x reference)
//
#include <hip/hip_runtime.h>
#include <hip/hip_fp16.h>

// Problem constants (from reference)
constexpr int N_FRAMES   = 2000;
constexpr int BATCH      = 32;
constexpr int TARGET_LEN = 1000;
constexpr int VOCAB      = 256;
constexpr int NTH        = 256;   // 4 waves per block
constexpr int CPT        = 4;     // columns per thread (256*4 = 1024 >= 1000)
#define NEGF (-1e30f)

// addrspace(1) pointers => guaranteed global_load (vmcnt only, never flat).
// NOTE: only scalar element types (float, ull) — HIP vector types (uint2 etc.)
// have member operator= that can't bind addrspace(1) references (R4 failure).
typedef __attribute__((address_space(1))) const float* gcfp;
typedef __attribute__((address_space(1))) const unsigned long long* gcu64;

// logaddexp in log2 domain: dst = E*log2e + max(A,U) + log2(1 + 2^(-|A-U|))
// (__builtin_amdgcn_logf == v_log_f32 == log2; verified by R3 absmax 0.0)
#define CELL(dst, A, U, E)                                            \
    {                                                                 \
        const float m_ = fmaxf((A), (U));                             \
        const float d_ = (A) - (U);                                   \
        const float p_ = __builtin_amdgcn_exp2f(-fabsf(d_));          \
        const float l_ = __builtin_amdgcn_logf(1.0f + p_);            \
        (dst) = fmaf((E), L2E, m_ + l_);                              \
    }

// ---------------- Phase 1: massively parallel emit gather ----------------
// emit[b][i][col] = (fp16) scores[i, b, tgt[b][min(col,999)]], col in [0,1024)
// One block per (i, b); thread t handles cols 4t..4t+3, packed 8B store.
__global__ __launch_bounds__(256)
void gather_emit(const float* __restrict__ scores,
                 const int*   __restrict__ targets,
                 __half*      __restrict__ emit)
{
    const int i = blockIdx.x;
    const int b = blockIdx.y;
    const int t = threadIdx.x;

    const gcfp gsc = (gcfp)scores;
    const unsigned sbase = (unsigned)(i * BATCH * VOCAB + b * VOCAB);

    int tk0, tk1, tk2, tk3;
    if (t < TARGET_LEN / 4) {                       // cols 4t..4t+3 all valid
        const int4 tk = *(const int4*)&targets[b * TARGET_LEN + 4 * t];  // 16B aligned
        tk0 = tk.x; tk1 = tk.y; tk2 = tk.z; tk3 = tk.w;
    } else {
        tk0 = tk1 = tk2 = tk3 = targets[b * TARGET_LEN + TARGET_LEN - 1];
    }

    const float e0 = gsc[sbase + (unsigned)tk0];
    const float e1 = gsc[sbase + (unsigned)tk1];
    const float e2 = gsc[sbase + (unsigned)tk2];
    const float e3 = gsc[sbase + (unsigned)tk3];

    const unsigned long long h0 = __half_as_ushort(__float2half_rn(e0));
    const unsigned long long h1 = __half_as_ushort(__float2half_rn(e1));
    const unsigned long long h2 = __half_as_ushort(__float2half_rn(e2));
    const unsigned long long h3 = __half_as_ushort(__float2half_rn(e3));

    const unsigned long long u = h0 | (h1 << 16) | (h2 << 32) | (h3 << 48);
    *(unsigned long long*)(emit + (((size_t)(b * N_FRAMES + i)) << 10) + 4 * t) = u;
}

// ---------------- Phase 2: serial DP, coalesced emit reads ----------------
// One block (4 waves) per batch item; thread t owns cols 4t..4t+3.
// Emit via 8-deep register ring of u64 (vmcnt-only). No LDS gathers.
__global__ __launch_bounds__(NTH)
void align_dp_pre(const __half* __restrict__ emit,
                  const int*    __restrict__ in_len,
                  const int*    __restrict__ tg_len,
                  float*        __restrict__ ws_final)
{
    constexpr float L2E = 1.44269504088896340736f;
    constexpr float LN2 = 0.69314718055994530942f;

    const int b    = blockIdx.x;
    const int t    = threadIdx.x;
    const int lane = t & 63;
    const int w    = t >> 6;

    __shared__ float bnd[2][4];   // wave-boundary col values, double buffered

    const int inlen = in_len[b];
    const int tlen  = tg_len[b];
    const int fth   = (tlen - 1) >> 2;
    const int fcc   = (tlen - 1) & 3;

    // u64 index: i*256 + t  (each u64 = 4 packed fp16 emit values)
    const gcu64 gem = (gcu64)(emit + (((size_t)b * N_FRAMES) << 10));

    // row 0 (log2 domain): only col 0 live
    float prev0 = NEGF, prev1 = NEGF, prev2 = NEGF, prev3 = NEGF;
    if (t == 0)
        prev0 = __half2float(emit[((size_t)b * N_FRAMES) << 10]) * L2E;
    if (lane == 63) bnd[0][w] = NEGF;

    // emit ring: rows 1..8 in flight
    unsigned long long er[8];
#pragma unroll
    for (int k = 0; k < 8; ++k) er[k] = gem[(1 + k) * 256 + t];

#define STEP(K)                                                                         \
    {                                                                                   \
        const int i = ib + (K);                                                         \
        if (i < N_FRAMES) {                                                             \
            /* drain own lds ops (bnd write/shfl), raw barrier: vmcnt ring survives */  \
            asm volatile("s_waitcnt lgkmcnt(0)" ::: "memory");                          \
            __builtin_amdgcn_s_barrier();                                               \
            asm volatile("" ::: "memory");                                              \
            const float fromLds = (w > 0) ? bnd[(i - 1) & 1][w - 1] : NEGF;             \
            const float sh = __shfl_up(prev3, 1);                                       \
            const unsigned long long u = er[K];                                         \
            if (i + 8 < N_FRAMES) er[K] = gem[(i + 8) * 256 + t];                       \
            const float e0 = __half2float(__ushort_as_half((unsigned short)(u & 0xffffu)));         \
            const float e1 = __half2float(__ushort_as_half((unsigned short)((u >> 16) & 0xffffu))); \
            const float e2 = __half2float(__ushort_as_half((unsigned short)((u >> 32) & 0xffffu))); \
            const float e3 = __half2float(__ushort_as_half((unsigned short)(u >> 48)));             \
            float cur0, cur1, cur2, cur3;                                               \
            CELL(cur1, prev0, prev1, e1);                                               \
            CELL(cur2, prev1, prev2, e2);                                               \
            CELL(cur3, prev2, prev3, e3);                                               \
            const float left = (lane == 0) ? fromLds : sh;                              \
            CELL(cur0, left, prev0, e0);                                                \
            if (lane == 63) bnd[i & 1][w] = cur3;                                       \
            if (i == inlen - 1 && t == fth) {                                           \
                const float v = (fcc == 0) ? cur0 : (fcc == 1) ? cur1                   \
                              : (fcc == 2) ? cur2 : cur3;                               \
                ws_final[b] = v * LN2;                                                  \
            }                                                                           \
            prev0 = cur0; prev1 = cur1; prev2 = cur2; prev3 = cur3;                     \
        }                                                                               \
    }

    for (int ib = 1; ib < N_FRAMES; ib += 8) {
        STEP(0) STEP(1) STEP(2) STEP(3) STEP(4) STEP(5) STEP(6) STEP(7)
    }
#undef STEP
}

// ---------------- Fallback (verified R3 kernel): LDS-gather DP ----------------
__global__ __launch_bounds__(NTH)
void align_dp4(const float* __restrict__ scores,   // [N, B, V]
               const int*   __restrict__ targets,  // [B, T]
               const int*   __restrict__ in_len,   // [B]
               const int*   __restrict__ tg_len,   // [B]
               float*       __restrict__ ws_final) // [B]
{
    constexpr float L2E = 1.44269504088896340736f;
    constexpr float LN2 = 0.69314718055994530942f;

    const int b    = blockIdx.x;
    const int t    = threadIdx.x;
    const int lane = t & 63;
    const int w    = t >> 6;

    __shared__ float elds[4][VOCAB];
    __shared__ float bnd[2][8];

    const int inlen = in_len[b];
    const int tlen  = tg_len[b];

    const gcfp gsc = (gcfp)scores;
    const unsigned base = (unsigned)(b * VOCAB);
    constexpr unsigned ROWW = (unsigned)(BATCH * VOCAB);

    int tok[CPT];
#pragma unroll
    for (int c = 0; c < CPT; ++c) {
        const int col = t * CPT + c;
        tok[c] = targets[b * TARGET_LEN + (col < TARGET_LEN ? col : TARGET_LEN - 1)];
    }

    float prev[CPT];
#pragma unroll
    for (int c = 0; c < CPT; ++c) prev[c] = NEGF;
    if (t == 0) prev[0] = gsc[base + (unsigned)tok[0]] * L2E;

    elds[1][t] = gsc[1u * ROWW + base + (unsigned)t];
    elds[2][t] = gsc[2u * ROWW + base + (unsigned)t];
    if (lane == 63) bnd[0][w] = NEGF;

    float g[4];
    g[3] = gsc[3u * ROWW + base + (unsigned)t];
    g[0] = gsc[4u * ROWW + base + (unsigned)t];
    g[1] = gsc[5u * ROWW + base + (unsigned)t];
    g[2] = gsc[6u * ROWW + base + (unsigned)t];

    const int fth = (tlen - 1) >> 2;
    const int fcc = (tlen - 1) & 3;

#define STEP(K)                                                                    \
    {                                                                              \
        const int i = ib + (K);                                                    \
        if (i < N_FRAMES) {                                                        \
            asm volatile("s_waitcnt lgkmcnt(0)" ::: "memory");                     \
            __builtin_amdgcn_s_barrier();                                          \
            asm volatile("" ::: "memory");                                         \
            const int sl = i & 3;                                                  \
            const float ec0 = elds[sl][tok[0]];                                    \
            const float ec1 = elds[sl][tok[1]];                                    \
            const float ec2 = elds[sl][tok[2]];                                    \
            const float ec3 = elds[sl][tok[3]];                                    \
            const float fromLds = (w > 0) ? bnd[(i - 1) & 1][w - 1] : NEGF;        \
            if (i + 2 < N_FRAMES) elds[(i + 2) & 3][t] = g[((K) + 3) & 3];         \
            if (i + 6 < N_FRAMES)                                                  \
                g[((K) + 3) & 3] = gsc[(unsigned)(i + 6) * ROWW + base + (unsigned)t]; \
            const float sh   = __shfl_up(prev[3], 1);                              \
            const float left = (lane == 0) ? fromLds : sh;                         \
            float cur0, cur1, cur2, cur3;                                          \
            CELL(cur0, left,    prev[0], ec0);                                     \
            CELL(cur1, prev[0], prev[1], ec1);                                     \
            CELL(cur2, prev[1], prev[2], ec2);                                     \
            CELL(cur3, prev[2], prev[3], ec3);                                     \
            if (lane == 63) bnd[i & 1][w] = cur3;                                  \
            if (i == inlen - 1 && t == fth) {                                      \
                const float v = (fcc == 0) ? cur0 : (fcc == 1) ? cur1              \
                              : (fcc == 2) ? cur2 : cur3;                          \
                ws_final[b] = v * LN2;                                             \
            }                                                                      \
            prev[0] = cur0; prev[1] = cur1; prev[2] = cur2; prev[3] = cur3;        \
        }                                                                          \
    }

    for (int ib = 1; ib < N_FRAMES; ib += 4) {
        STEP(0) STEP(1) STEP(2) STEP(3)
    }
#undef STEP
}

// Final scalar: out = -sum(ws_final)/BATCH. Unconditional write.
__global__ void reduce_kernel(const float* __restrict__ ws_final, float* __restrict__ out)
{
    if (threadIdx.x == 0 && blockIdx.x == 0) {
        float s = 0.0f;
        for (int b = 0; b < BATCH; ++b) s += ws_final[b];
        out[0] = -s / (float)BATCH;
    }
}

extern "C" void kernel_launch(void* const* d_in, const int* in_sizes, int n_in,
                              void* d_out, int out_size, void* d_ws, size_t ws_size,
                              hipStream_t stream)
{
    const float* scores  = (const float*)d_in[0];
    const int*   targets = (const int*)  d_in[1];
    const int*   in_len  = (const int*)  d_in[2];
    const int*   tg_len  = (const int*)  d_in[3];
    float*       out     = (float*)d_out;
    float*       ws_fin  = (float*)d_ws;                     // [0,128): per-batch finals

    const size_t emit_bytes = (size_t)BATCH * N_FRAMES * 1024 * sizeof(__half);
    const size_t need = 256 + emit_bytes;

    if (ws_size >= need) {
        __half* emit = (__half*)((char*)d_ws + 256);
        dim3 ggrid(N_FRAMES, BATCH);
        gather_emit<<<ggrid, 256, 0, stream>>>(scores, targets, emit);
        align_dp_pre<<<BATCH, NTH, 0, stream>>>(emit, in_len, tg_len, ws_fin);
    } else {
        align_dp4<<<BATCH, NTH, 0, stream>>>(scores, targets, in_len, tg_len, ws_fin);
    }
    reduce_kernel<<<1, 64, 0, stream>>>(ws_fin, out);
}

// Round 7
// 775.850 us; speedup vs baseline: 1.3163x; 1.3163x over previous
//
#include <hip/hip_runtime.h>
#include <hip/hip_fp16.h>

// Problem constants (from reference)
constexpr int N_FRAMES   = 2000;
constexpr int BATCH      = 32;
constexpr int TARGET_LEN = 1000;
constexpr int VOCAB      = 256;
constexpr int RING       = 4;     // emit rows in flight (register ring)
#define NEGF (-1e30f)

// addrspace(1) pointers => guaranteed global_load (vmcnt only, never flat).
// Scalar element types only (HIP vector types can't bind addrspace(1) refs).
typedef __attribute__((address_space(1))) const float* gcfp;
typedef __attribute__((address_space(1))) const unsigned long long* gcu64;

// log2-domain logaddexp cell, emit E already premultiplied by log2(e):
//   dst = E + max(A,U) + log2(1 + 2^(-|A-U|))
#define LSECELL(dst, A, U, E)                                         \
    {                                                                 \
        const float m_ = fmaxf((A), (U));                             \
        const float d_ = (A) - (U);                                   \
        const float x_ = __builtin_amdgcn_exp2f(-fabsf(d_));          \
        const float l_ = __builtin_amdgcn_logf(1.0f + x_);            \
        (dst) = (E) + (m_ + l_);                                      \
    }

#define H2F(us) __half2float(__ushort_as_half((unsigned short)(us)))

// ---------------- Phase 1: massively parallel emit gather ----------------
// emit[b][i][col] = fp16( scores[i,b,tgt[b][min(col,999)]] * log2(e) )
// One block per (i, b); thread t handles cols 4t..4t+3, packed 8B store.
__global__ __launch_bounds__(256)
void gather_emit(const float* __restrict__ scores,
                 const int*   __restrict__ targets,
                 __half*      __restrict__ emit)
{
    constexpr float L2E = 1.44269504088896340736f;
    const int i = blockIdx.x;
    const int b = blockIdx.y;
    const int t = threadIdx.x;

    const gcfp gsc = (gcfp)scores;
    const unsigned sbase = (unsigned)(i * BATCH * VOCAB + b * VOCAB);

    int tk0, tk1, tk2, tk3;
    if (t < TARGET_LEN / 4) {                       // cols 4t..4t+3 all valid
        const int4 tk = *(const int4*)&targets[b * TARGET_LEN + 4 * t];  // 16B aligned
        tk0 = tk.x; tk1 = tk.y; tk2 = tk.z; tk3 = tk.w;
    } else {
        tk0 = tk1 = tk2 = tk3 = targets[b * TARGET_LEN + TARGET_LEN - 1];
    }

    const float e0 = gsc[sbase + (unsigned)tk0] * L2E;
    const float e1 = gsc[sbase + (unsigned)tk1] * L2E;
    const float e2 = gsc[sbase + (unsigned)tk2] * L2E;
    const float e3 = gsc[sbase + (unsigned)tk3] * L2E;

    const unsigned long long h0 = __half_as_ushort(__float2half_rn(e0));
    const unsigned long long h1 = __half_as_ushort(__float2half_rn(e1));
    const unsigned long long h2 = __half_as_ushort(__float2half_rn(e2));
    const unsigned long long h3 = __half_as_ushort(__float2half_rn(e3));

    const unsigned long long u = h0 | (h1 << 16) | (h2 << 32) | (h3 << 48);
    *(unsigned long long*)(emit + (((size_t)(b * N_FRAMES + i)) << 10) + 4 * t) = u;
}

// ---------------- Phase 2: serial DP, ONE WAVE per batch item ----------------
// Lane l owns cols [16l, 16l+16). Whole DP row in registers. No barriers, no
// LDS tiles; one __shfl_up per row (consumed only by cell 0 -> latency hidden
// under the 15 independent cells). Emit read coalesced via 4xu64 per lane per
// row through a statically-indexed 4-row register ring (vmcnt-only loads).
__global__ __launch_bounds__(64)
void align_dp_wave(const __half* __restrict__ emit,   // [B][N][1024] premult
                   const int*    __restrict__ in_len,
                   const int*    __restrict__ tg_len,
                   float*        __restrict__ ws_final)
{
    constexpr float LN2 = 0.69314718055994530942f;

    const int b    = blockIdx.x;
    const int lane = threadIdx.x;

    const int inlen = in_len[b];
    const int tlen  = tg_len[b];
    const int fl    = (tlen - 1) >> 4;   // lane owning final column
    const int fc    = (tlen - 1) & 15;   // its cell index (STATIC selects only!)

    // u64 index: i*256 + lane*4 + k   (4 packed fp16 per u64)
    const gcu64 gem = (gcu64)(emit + (((size_t)b * N_FRAMES) << 10));

    // ---- row 0: only global col 0 live (value already *L2E in emit) ----
    float pr0 = NEGF, pr1 = NEGF, pr2 = NEGF, pr3 = NEGF,
          pr4 = NEGF, pr5 = NEGF, pr6 = NEGF, pr7 = NEGF,
          pr8 = NEGF, pr9 = NEGF, pr10 = NEGF, pr11 = NEGF,
          pr12 = NEGF, pr13 = NEGF, pr14 = NEGF, pr15 = NEGF;
    if (lane == 0) pr0 = H2F((unsigned short)(gem[0] & 0xffffull));

    // select-from-16 with static indices only (avoid scratch: rule #20)
#define SELSTORE(c0,c1,c2,c3,c4,c5,c6,c7,c8,c9,c10,c11,c12,c13,c14,c15)  \
    {                                                                    \
        float v_ = c0;                                                   \
        if (fc == 1)  v_ = c1;  if (fc == 2)  v_ = c2;                   \
        if (fc == 3)  v_ = c3;  if (fc == 4)  v_ = c4;                   \
        if (fc == 5)  v_ = c5;  if (fc == 6)  v_ = c6;                   \
        if (fc == 7)  v_ = c7;  if (fc == 8)  v_ = c8;                   \
        if (fc == 9)  v_ = c9;  if (fc == 10) v_ = c10;                  \
        if (fc == 11) v_ = c11; if (fc == 12) v_ = c12;                  \
        if (fc == 13) v_ = c13; if (fc == 14) v_ = c14;                  \
        if (fc == 15) v_ = c15;                                          \
        ws_final[b] = v_ * LN2;                                          \
    }

    if (inlen == 1 && lane == fl)   // impossible for this setup; cheap safety
        SELSTORE(pr0,pr1,pr2,pr3,pr4,pr5,pr6,pr7,pr8,pr9,pr10,pr11,pr12,pr13,pr14,pr15);

    // ---- ring fill: emit rows 1..RING ----
    unsigned long long ring[RING][4];
#pragma unroll
    for (int k = 0; k < RING; ++k) {
#pragma unroll
        for (int q = 0; q < 4; ++q)
            ring[k][q] = gem[((1 + k) << 8) + (lane << 2) + q];
    }

#define STEP(K)                                                                      \
    {                                                                                \
        const int i = ib + (K);                                                      \
        if (i < N_FRAMES) {                                                          \
            const float sh   = __shfl_up(pr15, 1);                                   \
            const float left = (lane == 0) ? NEGF : sh;                              \
            const unsigned long long u0 = ring[K][0];                                \
            const unsigned long long u1 = ring[K][1];                                \
            const unsigned long long u2 = ring[K][2];                                \
            const unsigned long long u3 = ring[K][3];                                \
            if (i + RING < N_FRAMES) {                                               \
                ring[K][0] = gem[((i + RING) << 8) + (lane << 2) + 0];               \
                ring[K][1] = gem[((i + RING) << 8) + (lane << 2) + 1];               \
                ring[K][2] = gem[((i + RING) << 8) + (lane << 2) + 2];               \
                ring[K][3] = gem[((i + RING) << 8) + (lane << 2) + 3];               \
            }                                                                        \
            const float e0  = H2F(u0);        const float e1  = H2F(u0 >> 16);       \
            const float e2  = H2F(u0 >> 32);  const float e3  = H2F(u0 >> 48);       \
            const float e4  = H2F(u1);        const float e5  = H2F(u1 >> 16);       \
            const float e6  = H2F(u1 >> 32);  const float e7  = H2F(u1 >> 48);       \
            const float e8  = H2F(u2);        const float e9  = H2F(u2 >> 16);       \
            const float e10 = H2F(u2 >> 32);  const float e11 = H2F(u2 >> 48);       \
            const float e12 = H2F(u3);        const float e13 = H2F(u3 >> 16);       \
            const float e14 = H2F(u3 >> 32);  const float e15 = H2F(u3 >> 48);       \
            float c0,c1,c2,c3,c4,c5,c6,c7,c8,c9,c10,c11,c12,c13,c14,c15;             \
            LSECELL(c1,  pr0,  pr1,  e1);  LSECELL(c2,  pr1,  pr2,  e2);             \
            LSECELL(c3,  pr2,  pr3,  e3);  LSECELL(c4,  pr3,  pr4,  e4);             \
            LSECELL(c5,  pr4,  pr5,  e5);  LSECELL(c6,  pr5,  pr6,  e6);             \
            LSECELL(c7,  pr6,  pr7,  e7);  LSECELL(c8,  pr7,  pr8,  e8);             \
            LSECELL(c9,  pr8,  pr9,  e9);  LSECELL(c10, pr9,  pr10, e10);            \
            LSECELL(c11, pr10, pr11, e11); LSECELL(c12, pr11, pr12, e12);            \
            LSECELL(c13, pr12, pr13, e13); LSECELL(c14, pr13, pr14, e14);            \
            LSECELL(c15, pr14, pr15, e15); LSECELL(c0,  left, pr0,  e0);             \
            if (i == inlen - 1 && lane == fl)                                        \
                SELSTORE(c0,c1,c2,c3,c4,c5,c6,c7,c8,c9,c10,c11,c12,c13,c14,c15);     \
            pr0=c0;  pr1=c1;  pr2=c2;  pr3=c3;  pr4=c4;  pr5=c5;  pr6=c6;  pr7=c7;   \
            pr8=c8;  pr9=c9;  pr10=c10; pr11=c11; pr12=c12; pr13=c13; pr14=c14;      \
            pr15=c15;                                                                \
        }                                                                            \
    }

    for (int ib = 1; ib < N_FRAMES; ib += RING) {
        STEP(0) STEP(1) STEP(2) STEP(3)
    }
#undef STEP
#undef SELSTORE
}

// Final scalar: out = -sum(ws_final)/BATCH. Unconditional write.
__global__ void reduce_kernel(const float* __restrict__ ws_final, float* __restrict__ out)
{
    if (threadIdx.x == 0 && blockIdx.x == 0) {
        float s = 0.0f;
        for (int b = 0; b < BATCH; ++b) s += ws_final[b];
        out[0] = -s / (float)BATCH;
    }
}

// ---------------- Fallback (verified R3 kernel) if ws too small ----------------
#define CELL(dst, A, U, E)                                            \
    {                                                                 \
        const float m_ = fmaxf((A), (U));                             \
        const float d_ = (A) - (U);                                   \
        const float p_ = __builtin_amdgcn_exp2f(-fabsf(d_));          \
        const float l_ = __builtin_amdgcn_logf(1.0f + p_);            \
        (dst) = fmaf((E), L2E, m_ + l_);                              \
    }

__global__ __launch_bounds__(256)
void align_dp4(const float* __restrict__ scores,
               const int*   __restrict__ targets,
               const int*   __restrict__ in_len,
               const int*   __restrict__ tg_len,
               float*       __restrict__ ws_final)
{
    constexpr float L2E = 1.44269504088896340736f;
    constexpr float LN2 = 0.69314718055994530942f;

    const int b    = blockIdx.x;
    const int t    = threadIdx.x;
    const int lane = t & 63;
    const int w    = t >> 6;

    __shared__ float elds[4][VOCAB];
    __shared__ float bnd[2][8];

    const int inlen = in_len[b];
    const int tlen  = tg_len[b];

    const gcfp gsc = (gcfp)scores;
    const unsigned base = (unsigned)(b * VOCAB);
    constexpr unsigned ROWW = (unsigned)(BATCH * VOCAB);

    int tok[4];
#pragma unroll
    for (int c = 0; c < 4; ++c) {
        const int col = t * 4 + c;
        tok[c] = targets[b * TARGET_LEN + (col < TARGET_LEN ? col : TARGET_LEN - 1)];
    }

    float prev[4];
#pragma unroll
    for (int c = 0; c < 4; ++c) prev[c] = NEGF;
    if (t == 0) prev[0] = gsc[base + (unsigned)tok[0]] * L2E;

    elds[1][t] = gsc[1u * ROWW + base + (unsigned)t];
    elds[2][t] = gsc[2u * ROWW + base + (unsigned)t];
    if (lane == 63) bnd[0][w] = NEGF;

    float g[4];
    g[3] = gsc[3u * ROWW + base + (unsigned)t];
    g[0] = gsc[4u * ROWW + base + (unsigned)t];
    g[1] = gsc[5u * ROWW + base + (unsigned)t];
    g[2] = gsc[6u * ROWW + base + (unsigned)t];

    const int fth = (tlen - 1) >> 2;
    const int fcc = (tlen - 1) & 3;

#define STEP(K)                                                                    \
    {                                                                              \
        const int i = ib + (K);                                                    \
        if (i < N_FRAMES) {                                                        \
            asm volatile("s_waitcnt lgkmcnt(0)" ::: "memory");                     \
            __builtin_amdgcn_s_barrier();                                          \
            asm volatile("" ::: "memory");                                         \
            const int sl = i & 3;                                                  \
            const float ec0 = elds[sl][tok[0]];                                    \
            const float ec1 = elds[sl][tok[1]];                                    \
            const float ec2 = elds[sl][tok[2]];                                    \
            const float ec3 = elds[sl][tok[3]];                                    \
            const float fromLds = (w > 0) ? bnd[(i - 1) & 1][w - 1] : NEGF;        \
            if (i + 2 < N_FRAMES) elds[(i + 2) & 3][t] = g[((K) + 3) & 3];         \
            if (i + 6 < N_FRAMES)                                                  \
                g[((K) + 3) & 3] = gsc[(unsigned)(i + 6) * ROWW + base + (unsigned)t]; \
            const float sh   = __shfl_up(prev[3], 1);                              \
            const float left = (lane == 0) ? fromLds : sh;                         \
            float cur0, cur1, cur2, cur3;                                          \
            CELL(cur0, left,    prev[0], ec0);                                     \
            CELL(cur1, prev[0], prev[1], ec1);                                     \
            CELL(cur2, prev[1], prev[2], ec2);                                     \
            CELL(cur3, prev[2], prev[3], ec3);                                     \
            if (lane == 63) bnd[i & 1][w] = cur3;                                  \
            if (i == inlen - 1 && t == fth) {                                      \
                const float v = (fcc == 0) ? cur0 : (fcc == 1) ? cur1              \
                              : (fcc == 2) ? cur2 : cur3;                          \
                ws_final[b] = v * LN2;                                             \
            }                                                                      \
            prev[0] = cur0; prev[1] = cur1; prev[2] = cur2; prev[3] = cur3;        \
        }                                                                          \
    }

    for (int ib = 1; ib < N_FRAMES; ib += 4) {
        STEP(0) STEP(1) STEP(2) STEP(3)
    }
#undef STEP
}

extern "C" void kernel_launch(void* const* d_in, const int* in_sizes, int n_in,
                              void* d_out, int out_size, void* d_ws, size_t ws_size,
                              hipStream_t stream)
{
    const float* scores  = (const float*)d_in[0];
    const int*   targets = (const int*)  d_in[1];
    const int*   in_len  = (const int*)  d_in[2];
    const int*   tg_len  = (const int*)  d_in[3];
    float*       out     = (float*)d_out;
    float*       ws_fin  = (float*)d_ws;                     // [0,256): per-batch finals

    const size_t emit_bytes = (size_t)BATCH * N_FRAMES * 1024 * sizeof(__half);
    const size_t need = 256 + emit_bytes;

    if (ws_size >= need) {
        __half* emit = (__half*)((char*)d_ws + 256);
        dim3 ggrid(N_FRAMES, BATCH);
        gather_emit<<<ggrid, 256, 0, stream>>>(scores, targets, emit);
        align_dp_wave<<<BATCH, 64, 0, stream>>>(emit, in_len, tg_len, ws_fin);
    } else {
        align_dp4<<<BATCH, 256, 0, stream>>>(scores, targets, in_len, tg_len, ws_fin);
    }
    reduce_kernel<<<1, 64, 0, stream>>>(ws_fin, out);
}